// Round 6
// baseline (144.766 us; speedup 1.0000x reference)
//
#include <hip/hip_runtime.h>

#define Bc 16
#define Hc 512
#define Wc 8192
#define NMAX 64
#define CPB 1024   // columns per block (256 threads x 4)
#define RPB 16     // rows per block

typedef float f32x4 __attribute__((ext_vector_type(4)));

// Kernel 1 (tiny): per-batch table build with a wave-parallel scan.
// table[b][i] = {s, sn, en, flags}; flags bit0 = valid, bit1 = sep-eligible.
__global__ __launch_bounds__(64) void setup_kernel(
    const int* __restrict__ xi,    // (B, NMAX, 2) int32
    const int* __restrict__ Narr,  // (B,) int32
    int4* __restrict__ table,      // (B, NMAX) int4 [workspace]
    float* __restrict__ xi_out)    // (B, NMAX, 2) as float32
{
    const int b = blockIdx.x;
    const int lane = threadIdx.x;
    const int Nb = Narr[b];

    const int s = xi[b * NMAX * 2 + lane * 2 + 0];
    const int e = xi[b * NMAX * 2 + lane * 2 + 1];
    const int valid = (lane < Nb) ? 1 : 0;
    int w = e - s;
    if (w < 0) w = 0;
    if (!valid) w = 0;

    // inclusive prefix sum across the 64-lane wave
    int c = w;
    #pragma unroll
    for (int d = 1; d < 64; d <<= 1) {
        int t = __shfl_up(c, d);
        if (lane >= d) c += t;
    }
    const int sn = c - w + lane;
    const int en = c + lane;
    const int flags = valid | (((valid != 0) & (lane < Nb - 1)) ? 2 : 0);

    table[b * NMAX + lane] = make_int4(s, sn, en, flags);
    xi_out[b * NMAX * 2 + lane * 2 + 0] = valid ? (float)sn : 0.0f;
    xi_out[b * NMAX * 2 + lane * 2 + 1] = valid ? (float)en : 0.0f;
}

// Kernel 2: streaming apply with wave-uniform zero fast path.
__global__ __launch_bounds__(256) void apply_kernel(
    const float* __restrict__ x,
    const int4* __restrict__ table,
    const float* __restrict__ sep_param,
    float* __restrict__ out_x)
{
    const int tid = threadIdx.x;
    const int colchunk = blockIdx.x;
    const int rowchunk = blockIdx.y;
    const int b = blockIdx.z;

    __shared__ int4 s_tab[NMAX];
    if (tid < NMAX) s_tab[tid] = table[b * NMAX + tid];
    __syncthreads();

    // ---- per-thread column map (registers, computed once) ----
    const int col0 = colchunk * CPB + tid * 4;

    int m0, m1, m2, m3;
    {
        int mm[4];
        #pragma unroll
        for (int c = 0; c < 4; ++c) {
            const int col = col0 + c;
            // searchsorted(en, col, side='right')
            int lo = 0, hi = NMAX;
            while (lo < hi) {
                int mid = (lo + hi) >> 1;
                if (s_tab[mid].z > col) hi = mid; else lo = mid + 1;
            }
            const int j = (lo < NMAX - 1) ? lo : (NMAX - 1);
            const int4 T = s_tab[j];
            int v = -1;  // zero
            if ((T.w & 1) && col >= T.y && col < T.z) {
                int src = T.x + (col - T.y);
                if (src < 0) src = 0;
                if (src > Wc - 1) src = Wc - 1;
                v = src;
            } else if (j >= 1) {
                const int4 P = s_tab[j - 1];
                if ((P.w & 2) && P.z == col) v = -2;  // separator
            }
            mm[c] = v;
        }
        m0 = mm[0]; m1 = mm[1]; m2 = mm[2]; m3 = mm[3];
    }

    const long long base0 = ((long long)b * Hc + (long long)rowchunk * RPB) * (long long)Wc;

    // ---- wave-uniform zero fast path (the packed-right tail) ----
    const bool hasdata = (m0 != -1) | (m1 != -1) | (m2 != -1) | (m3 != -1);
    if (__ballot(hasdata) == 0ULL) {
        const f32x4 z = (f32x4){0.f, 0.f, 0.f, 0.f};
        #pragma unroll
        for (int rr = 0; rr < RPB; ++rr) {
            __builtin_nontemporal_store(
                z, (f32x4*)(out_x + base0 + (long long)rr * Wc + col0));
        }
        return;
    }

    // ---- data path ----
    const float sep = sep_param[0];

    const bool contig  = (m0 >= 0) & (m1 == m0 + 1) & (m2 == m0 + 2) & (m3 == m0 + 3);
    const int a  = (m0 >= 0) ? (m0 >> 2) : 0;
    const int r  = (m0 >= 0) ? (m0 & 3) : 0;
    // r>0 implies m0+3 <= W-1 so a1 stays inside the row; r==0 -> a1=a.
    const int a1 = r ? (a + 1) : a;

    #pragma unroll 4
    for (int rr = 0; rr < RPB; ++rr) {
        const long long rowoff = base0 + (long long)rr * Wc;
        const float* __restrict__ xrow = x + rowoff;
        f32x4 v;
        if (contig) {
            const f32x4* __restrict__ p = (const f32x4*)xrow;
            const f32x4 A = __builtin_nontemporal_load(p + a);
            const f32x4 B = __builtin_nontemporal_load(p + a1);
            v.x = (r == 0) ? A.x : (r == 1) ? A.y : (r == 2) ? A.z : A.w;
            v.y = (r == 0) ? A.y : (r == 1) ? A.z : (r == 2) ? A.w : B.x;
            v.z = (r == 0) ? A.z : (r == 1) ? A.w : (r == 2) ? B.x : B.y;
            v.w = (r == 0) ? A.w : (r == 1) ? B.x : (r == 2) ? B.y : B.z;
        } else {
            v.x = (m0 >= 0) ? __builtin_nontemporal_load(xrow + m0) : ((m0 == -2) ? sep : 0.f);
            v.y = (m1 >= 0) ? __builtin_nontemporal_load(xrow + m1) : ((m1 == -2) ? sep : 0.f);
            v.z = (m2 >= 0) ? __builtin_nontemporal_load(xrow + m2) : ((m2 == -2) ? sep : 0.f);
            v.w = (m3 >= 0) ? __builtin_nontemporal_load(xrow + m3) : ((m3 == -2) ? sep : 0.f);
        }
        __builtin_nontemporal_store(v, (f32x4*)(out_x + rowoff + col0));
    }
}

extern "C" void kernel_launch(void* const* d_in, const int* in_sizes, int n_in,
                              void* d_out, int out_size, void* d_ws, size_t ws_size,
                              hipStream_t stream) {
    const float* x   = (const float*)d_in[0];
    const int*   xi  = (const int*)d_in[1];
    const int*   N   = (const int*)d_in[2];
    const float* sep = (const float*)d_in[3];

    float* out_x  = (float*)d_out;
    float* out_xi = out_x + (long long)Bc * Hc * Wc;
    int4*  table  = (int4*)d_ws;   // 16 KB

    setup_kernel<<<Bc, 64, 0, stream>>>(xi, N, table, out_xi);

    dim3 grid(Wc / CPB, Hc / RPB, Bc);   // (8, 32, 16) = 4096 blocks
    apply_kernel<<<grid, 256, 0, stream>>>(x, table, sep, out_x);
}

// Round 7
// 72.892 us; speedup vs baseline: 1.9860x; 1.9860x over previous
//
#include <hip/hip_runtime.h>

#define Bc 16
#define Hc 512
#define Wc 8192
#define NMAX 64
#define CPB 1024   // columns per block (256 threads x 4)
#define RPB 16     // rows per block

typedef float f32x4 __attribute__((ext_vector_type(4)));

// Fused kernel (R4 structure). Single delta vs R4: the 64-entry prefix sum is
// a wave-parallel __shfl_up scan on the first wave instead of a tid0 serial
// loop, and the two barriers collapse into one.
__global__ __launch_bounds__(256) void fused_compact_kernel(
    const float* __restrict__ x,
    const int* __restrict__ xi,    // (B, NMAX, 2) int32
    const int* __restrict__ Narr,  // (B,) int32
    const float* __restrict__ sep_param,
    float* __restrict__ out_x,     // (B, 1, H, W) float32
    float* __restrict__ out_xi)    // (B, NMAX, 2) as float32
{
    const int tid = threadIdx.x;
    const int colchunk = blockIdx.x;
    const int rowchunk = blockIdx.y;
    const int b = blockIdx.z;

    __shared__ int s_s[NMAX];
    __shared__ int s_sn[NMAX];
    __shared__ int s_en[NMAX];
    __shared__ int s_valid[NMAX];

    const int Nb = Narr[b];

    if (tid < NMAX) {   // entire first wave: tid == lane
        const int s = xi[b * NMAX * 2 + tid * 2 + 0];
        const int e = xi[b * NMAX * 2 + tid * 2 + 1];
        const int valid = (tid < Nb) ? 1 : 0;
        int w = e - s;
        if (w < 0) w = 0;
        if (!valid) w = 0;

        // inclusive prefix sum across the 64-lane wave
        int c = w;
        #pragma unroll
        for (int d = 1; d < 64; d <<= 1) {
            int t = __shfl_up(c, d);
            if (tid >= d) c += t;
        }
        s_s[tid] = s;
        s_valid[tid] = valid;
        s_sn[tid] = c - w + tid;
        s_en[tid] = c + tid;

        // xi_new output (once per batch)
        if (colchunk == 0 && rowchunk == 0) {
            out_xi[b * NMAX * 2 + tid * 2 + 0] = valid ? (float)(c - w + tid) : 0.0f;
            out_xi[b * NMAX * 2 + tid * 2 + 1] = valid ? (float)(c + tid) : 0.0f;
        }
    }
    __syncthreads();

    // ---- per-thread column map (registers, computed once) ----
    const int col0 = colchunk * CPB + tid * 4;

    int m0, m1, m2, m3;
    {
        int mm[4];
        #pragma unroll
        for (int c = 0; c < 4; ++c) {
            const int col = col0 + c;
            // searchsorted(en, col, side='right')
            int lo = 0, hi = NMAX;
            while (lo < hi) {
                int mid = (lo + hi) >> 1;
                if (s_en[mid] > col) hi = mid; else lo = mid + 1;
            }
            int j = (lo < NMAX - 1) ? lo : (NMAX - 1);
            int v = -1;  // zero
            if (s_valid[j] && col >= s_sn[j] && col < s_en[j]) {
                int src = s_s[j] + (col - s_sn[j]);
                if (src < 0) src = 0;
                if (src > Wc - 1) src = Wc - 1;
                v = src;
            } else if (j >= 1) {
                int i = j - 1;
                if (s_valid[i] && (i < Nb - 1) && s_en[i] == col) v = -2;  // sep
            }
            mm[c] = v;
        }
        m0 = mm[0]; m1 = mm[1]; m2 = mm[2]; m3 = mm[3];
    }

    const long long base0 = ((long long)b * Hc + (long long)rowchunk * RPB) * (long long)Wc;

    // ---- wave-uniform zero fast path (the packed-right tail) ----
    const bool hasdata = (m0 != -1) | (m1 != -1) | (m2 != -1) | (m3 != -1);
    if (__ballot(hasdata) == 0ULL) {
        const f32x4 z = (f32x4){0.f, 0.f, 0.f, 0.f};
        #pragma unroll
        for (int rr = 0; rr < RPB; ++rr) {
            __builtin_nontemporal_store(
                z, (f32x4*)(out_x + base0 + (long long)rr * Wc + col0));
        }
        return;
    }

    // ---- data path ----
    const float sep = sep_param[0];

    const bool contig  = (m0 >= 0) & (m1 == m0 + 1) & (m2 == m0 + 2) & (m3 == m0 + 3);
    const int a  = (m0 >= 0) ? (m0 >> 2) : 0;
    const int r  = (m0 >= 0) ? (m0 & 3) : 0;
    // r>0 implies m0+3 <= W-1 so a1 stays inside the row; r==0 -> a1=a.
    const int a1 = r ? (a + 1) : a;

    #pragma unroll 4
    for (int rr = 0; rr < RPB; ++rr) {
        const long long rowoff = base0 + (long long)rr * Wc;
        const float* __restrict__ xrow = x + rowoff;
        f32x4 v;
        if (contig) {
            const f32x4* __restrict__ p = (const f32x4*)xrow;
            const f32x4 A = p[a];
            const f32x4 B = p[a1];
            v.x = (r == 0) ? A.x : (r == 1) ? A.y : (r == 2) ? A.z : A.w;
            v.y = (r == 0) ? A.y : (r == 1) ? A.z : (r == 2) ? A.w : B.x;
            v.z = (r == 0) ? A.z : (r == 1) ? A.w : (r == 2) ? B.x : B.y;
            v.w = (r == 0) ? A.w : (r == 1) ? B.x : (r == 2) ? B.y : B.z;
        } else {
            v.x = (m0 >= 0) ? xrow[m0] : ((m0 == -2) ? sep : 0.f);
            v.y = (m1 >= 0) ? xrow[m1] : ((m1 == -2) ? sep : 0.f);
            v.z = (m2 >= 0) ? xrow[m2] : ((m2 == -2) ? sep : 0.f);
            v.w = (m3 >= 0) ? xrow[m3] : ((m3 == -2) ? sep : 0.f);
        }
        __builtin_nontemporal_store(v, (f32x4*)(out_x + rowoff + col0));
    }
}

extern "C" void kernel_launch(void* const* d_in, const int* in_sizes, int n_in,
                              void* d_out, int out_size, void* d_ws, size_t ws_size,
                              hipStream_t stream) {
    const float* x   = (const float*)d_in[0];
    const int*   xi  = (const int*)d_in[1];
    const int*   N   = (const int*)d_in[2];
    const float* sep = (const float*)d_in[3];

    float* out_x  = (float*)d_out;
    float* out_xi = out_x + (long long)Bc * Hc * Wc;

    dim3 grid(Wc / CPB, Hc / RPB, Bc);   // (8, 32, 16) = 4096 blocks
    fused_compact_kernel<<<grid, 256, 0, stream>>>(x, xi, N, sep, out_x, out_xi);
}

// Round 8
// 72.545 us; speedup vs baseline: 1.9955x; 1.0048x over previous
//
#include <hip/hip_runtime.h>

#define Bc 16
#define Hc 512
#define Wc 8192
#define NMAX 64
#define CPB 1024   // columns per block (256 threads x 4)
#define RPB 16     // rows per block

typedef float f32x4 __attribute__((ext_vector_type(4)));
typedef f32x4 f32x4u __attribute__((aligned(4)));   // under-aligned load alias

// Fused kernel (R7 structure). Single delta vs R7: the contiguous-run data
// path is ONE unaligned (4B-aligned) global_load_dwordx4 at xrow+m0 instead
// of two aligned loads + 8 cndmask selects.
__global__ __launch_bounds__(256) void fused_compact_kernel(
    const float* __restrict__ x,
    const int* __restrict__ xi,    // (B, NMAX, 2) int32
    const int* __restrict__ Narr,  // (B,) int32
    const float* __restrict__ sep_param,
    float* __restrict__ out_x,     // (B, 1, H, W) float32
    float* __restrict__ out_xi)    // (B, NMAX, 2) as float32
{
    const int tid = threadIdx.x;
    const int colchunk = blockIdx.x;
    const int rowchunk = blockIdx.y;
    const int b = blockIdx.z;

    __shared__ int s_s[NMAX];
    __shared__ int s_sn[NMAX];
    __shared__ int s_en[NMAX];
    __shared__ int s_valid[NMAX];

    const int Nb = Narr[b];

    if (tid < NMAX) {   // entire first wave: tid == lane
        const int s = xi[b * NMAX * 2 + tid * 2 + 0];
        const int e = xi[b * NMAX * 2 + tid * 2 + 1];
        const int valid = (tid < Nb) ? 1 : 0;
        int w = e - s;
        if (w < 0) w = 0;
        if (!valid) w = 0;

        // inclusive prefix sum across the 64-lane wave
        int c = w;
        #pragma unroll
        for (int d = 1; d < 64; d <<= 1) {
            int t = __shfl_up(c, d);
            if (tid >= d) c += t;
        }
        s_s[tid] = s;
        s_valid[tid] = valid;
        s_sn[tid] = c - w + tid;
        s_en[tid] = c + tid;

        // xi_new output (once per batch)
        if (colchunk == 0 && rowchunk == 0) {
            out_xi[b * NMAX * 2 + tid * 2 + 0] = valid ? (float)(c - w + tid) : 0.0f;
            out_xi[b * NMAX * 2 + tid * 2 + 1] = valid ? (float)(c + tid) : 0.0f;
        }
    }
    __syncthreads();

    // ---- per-thread column map (registers, computed once) ----
    const int col0 = colchunk * CPB + tid * 4;

    int m0, m1, m2, m3;
    {
        int mm[4];
        #pragma unroll
        for (int c = 0; c < 4; ++c) {
            const int col = col0 + c;
            // searchsorted(en, col, side='right')
            int lo = 0, hi = NMAX;
            while (lo < hi) {
                int mid = (lo + hi) >> 1;
                if (s_en[mid] > col) hi = mid; else lo = mid + 1;
            }
            int j = (lo < NMAX - 1) ? lo : (NMAX - 1);
            int v = -1;  // zero
            if (s_valid[j] && col >= s_sn[j] && col < s_en[j]) {
                int src = s_s[j] + (col - s_sn[j]);
                if (src < 0) src = 0;
                if (src > Wc - 1) src = Wc - 1;
                v = src;
            } else if (j >= 1) {
                int i = j - 1;
                if (s_valid[i] && (i < Nb - 1) && s_en[i] == col) v = -2;  // sep
            }
            mm[c] = v;
        }
        m0 = mm[0]; m1 = mm[1]; m2 = mm[2]; m3 = mm[3];
    }

    const long long base0 = ((long long)b * Hc + (long long)rowchunk * RPB) * (long long)Wc;

    // ---- wave-uniform zero fast path (the packed-right tail) ----
    const bool hasdata = (m0 != -1) | (m1 != -1) | (m2 != -1) | (m3 != -1);
    if (__ballot(hasdata) == 0ULL) {
        const f32x4 z = (f32x4){0.f, 0.f, 0.f, 0.f};
        #pragma unroll
        for (int rr = 0; rr < RPB; ++rr) {
            __builtin_nontemporal_store(
                z, (f32x4*)(out_x + base0 + (long long)rr * Wc + col0));
        }
        return;
    }

    // ---- data path ----
    const float sep = sep_param[0];

    const bool contig  = (m0 >= 0) & (m1 == m0 + 1) & (m2 == m0 + 2) & (m3 == m0 + 3);

    #pragma unroll 4
    for (int rr = 0; rr < RPB; ++rr) {
        const long long rowoff = base0 + (long long)rr * Wc;
        const float* __restrict__ xrow = x + rowoff;
        f32x4 v;
        if (contig) {
            // 4B-aligned vector load: legal on gfx950, same L1 traffic as
            // the old A/B pair, no alignment-select VALU.
            v = *(const f32x4u*)(xrow + m0);
        } else {
            v.x = (m0 >= 0) ? xrow[m0] : ((m0 == -2) ? sep : 0.f);
            v.y = (m1 >= 0) ? xrow[m1] : ((m1 == -2) ? sep : 0.f);
            v.z = (m2 >= 0) ? xrow[m2] : ((m2 == -2) ? sep : 0.f);
            v.w = (m3 >= 0) ? xrow[m3] : ((m3 == -2) ? sep : 0.f);
        }
        __builtin_nontemporal_store(v, (f32x4*)(out_x + rowoff + col0));
    }
}

extern "C" void kernel_launch(void* const* d_in, const int* in_sizes, int n_in,
                              void* d_out, int out_size, void* d_ws, size_t ws_size,
                              hipStream_t stream) {
    const float* x   = (const float*)d_in[0];
    const int*   xi  = (const int*)d_in[1];
    const int*   N   = (const int*)d_in[2];
    const float* sep = (const float*)d_in[3];

    float* out_x  = (float*)d_out;
    float* out_xi = out_x + (long long)Bc * Hc * Wc;

    dim3 grid(Wc / CPB, Hc / RPB, Bc);   // (8, 32, 16) = 4096 blocks
    fused_compact_kernel<<<grid, 256, 0, stream>>>(x, xi, N, sep, out_x, out_xi);
}